// Round 18
// baseline (39.408 us; speedup 1.0000x reference)
//
#include <hip/hip_runtime.h>

// RankingLoss: mean over rows of sum over ordered pairs (label_i-label_j>TOL)
// of log_sigmoid(logit_i - logit_j).
//
// Per unordered pair, with s = logit*log2e, E = 2^s, ld = lab_i - lab_j:
//   valid (|ld| > TOL):  contribution = -ln2 * (log2(E_i + E_j) - s_hi),
//   s_hi = s of the higher-LABEL side = (ld>0 ? s_i : s_j).
// Per-pair cost: 9 VALU + 1/8 v_log, ZERO exp (E staged per window).
//   p *= valid ? (E_i+E_j) : 1   (product of 8, <= 2^68: no overflow)
//   accS += valid ? s_hi : 0
// Flat circulant structure (r2/r4: measured == model within 1%):
//   j = (i+k) mod N, k in [1,1024]; k in [1,1023] covers each unordered pair
//   once; k=1024 twice -> kc==7 removes half of the kk=127 term.
// Grid: 64 rows x 8 i-chunks(256) x 8 k-chunks(128) = 4096 blocks.

#define NN 2048
#define BB 64
#define TOL 0.01f
#define BLK 256
#define KCHUNKS 8
#define ICHUNKS 8
#define GRID (BB * KCHUNKS * ICHUNKS)    // 4096
#define LOG2E 1.4426950408889634f

__device__ float g_partials[GRID];

__global__ __launch_bounds__(BLK) void rank_main(const float* __restrict__ logits,
                                                 const float* __restrict__ labels) {
    __shared__ float2 sls[384];          // (label, s) j-window
    __shared__ float  sE[384];           // E = 2^s j-window
    const int bid = blockIdx.x;
    const int row = bid >> 6;
    const int sub = bid & 63;
    const int ic = sub >> 3;             // 0..7
    const int kc = sub & 7;              // 0..7

    const float* lg = logits + (size_t)row * NN;
    const float* lb = labels + (size_t)row * NN;
    const int ibeg = ic * BLK;
    const int kbeg = kc * 128 + 1;
    const int jbeg = ibeg + kbeg;

    for (int x = threadIdx.x; x < 384; x += BLK) {
        int j = (jbeg + x) & (NN - 1);
        float s = lg[j] * LOG2E;
        sls[x] = make_float2(lb[j], s);
        sE[x]  = __builtin_amdgcn_exp2f(s);
    }
    __syncthreads();

    const int i = ibeg + threadIdx.x;
    const float lai = lb[i];
    const float si  = lg[i] * LOG2E;
    const float Ei  = __builtin_amdgcn_exp2f(si);

    float accL = 0.0f;                   // sum log2(E_i+E_j) over valid pairs
    float accS = 0.0f;                   // sum s_hi over valid pairs
#pragma unroll 2
    for (int kk0 = 0; kk0 < 128; kk0 += 8) {
        float p = 1.0f;
#pragma unroll
        for (int u = 0; u < 8; ++u) {
            float2 ls = sls[threadIdx.x + kk0 + u];
            float  Ej = sE[threadIdx.x + kk0 + u];
            float ld = lai - ls.x;
            bool valid = fabsf(ld) > TOL;            // exact reference predicate
            float term = valid ? (Ei + Ej) : 1.0f;
            p *= term;
            float sh = (ld > 0.0f) ? si : ls.y;
            accS += valid ? sh : 0.0f;
        }
        accL += __builtin_amdgcn_logf(p);            // v_log_f32 = log2
    }
    if (kc == KCHUNKS - 1) {
        // k=1024 (kk=127) visited at full weight from both endpoints; each
        // visit should count half -> remove the surplus half here.
        float2 ls = sls[threadIdx.x + 127];
        float  Ej = sE[threadIdx.x + 127];
        float ld = lai - ls.x;
        bool valid = fabsf(ld) > TOL;
        float term = valid ? (Ei + Ej) : 1.0f;
        accL -= 0.5f * __builtin_amdgcn_logf(term);
        float sh = (ld > 0.0f) ? si : ls.y;
        accS -= 0.5f * (valid ? sh : 0.0f);
    }

    float v = accL - accS;               // log2 units; final multiplies by -ln2

    for (int off = 32; off > 0; off >>= 1) v += __shfl_down(v, off);
    __shared__ float swave[BLK / 64];
    const int wid  = threadIdx.x >> 6;
    const int lane = threadIdx.x & 63;
    if (lane == 0) swave[wid] = v;
    __syncthreads();
    if (threadIdx.x == 0)
        g_partials[bid] = swave[0] + swave[1] + swave[2] + swave[3];
}

__global__ __launch_bounds__(BLK) void rank_final(float* __restrict__ out) {
    double v = 0.0;
    for (int idx = threadIdx.x; idx < GRID; idx += BLK) v += (double)g_partials[idx];
    for (int off = 32; off > 0; off >>= 1) v += __shfl_down(v, off);
    __shared__ double swave[BLK / 64];
    const int wid  = threadIdx.x >> 6;
    const int lane = threadIdx.x & 63;
    if (lane == 0) swave[wid] = v;
    __syncthreads();
    if (threadIdx.x == 0)
        out[0] = (float)((swave[0] + swave[1] + swave[2] + swave[3]) *
                         (-0.6931471805599453 / (double)BB));
}

extern "C" void kernel_launch(void* const* d_in, const int* in_sizes, int n_in,
                              void* d_out, int out_size, void* d_ws, size_t ws_size,
                              hipStream_t stream) {
    const float* logits = (const float*)d_in[0];
    const float* labels = (const float*)d_in[1];
    float* out = (float*)d_out;
    (void)in_sizes; (void)n_in; (void)out_size; (void)d_ws; (void)ws_size;

    rank_main<<<GRID, BLK, 0, stream>>>(logits, labels);
    rank_final<<<1, BLK, 0, stream>>>(out);
}